// Round 10
// baseline (475.136 us; speedup 1.0000x reference)
//
#include <hip/hip_runtime.h>
#include <hip/hip_bf16.h>
#include <math.h>

#define D 512
#define BB 4
#define TT 4096
#define KT 32

typedef __attribute__((ext_vector_type(8))) short short8v;
typedef __attribute__((ext_vector_type(4))) short short4v;
typedef __attribute__((ext_vector_type(4))) float float4v;

__device__ inline short f2bf(float x) {
    __hip_bfloat16 h = __float2bfloat16(x);
    return *reinterpret_cast<short*>(&h);
}

// ============ QKV projection: C[t][e] = alpha * sum_d x[t][d] * W[e][d], bf16 out ============
__global__ __launch_bounds__(256) void gemm_qkv(
    const float* __restrict__ x,
    const float* __restrict__ Wq, const float* __restrict__ Wk, const float* __restrict__ Wv,
    __hip_bfloat16* __restrict__ q, __hip_bfloat16* __restrict__ k, __hip_bfloat16* __restrict__ v)
{
    const float* W; __hip_bfloat16* C; float alpha;
    if (blockIdx.z == 0)      { W = Wq; C = q; alpha = 0.044194173824159216f; } // fold 1/sqrt(512)
    else if (blockIdx.z == 1) { W = Wk; C = k; alpha = 1.f; }
    else                      { W = Wv; C = v; alpha = 1.f; }

    __shared__ short As[64][72];   // +8 bf16 pad -> conflict-floor b128 reads
    __shared__ short Bs[64][72];
    const int tid = threadIdx.x;
    const int m0 = blockIdx.x * 64, n0 = blockIdx.y * 64;
    const int w = tid >> 6, lane = tid & 63, lm = lane & 15, g = lane >> 4;

    float4v acc[4];
    #pragma unroll
    for (int i = 0; i < 4; ++i) acc[i] = (float4v){0.f,0.f,0.f,0.f};

    for (int k0 = 0; k0 < 512; k0 += 64) {
        __syncthreads();
        #pragma unroll
        for (int u = 0; u < 4; ++u) {          // stage A (x), convert f32->bf16
            int ch = tid + 256*u;
            int r = ch >> 4, c = (ch & 15) * 4;
            float4 xv = *reinterpret_cast<const float4*>(x + (size_t)(m0 + r)*512 + k0 + c);
            short4v sv = { f2bf(xv.x), f2bf(xv.y), f2bf(xv.z), f2bf(xv.w) };
            *reinterpret_cast<short4v*>(&As[r][c]) = sv;
        }
        #pragma unroll
        for (int u = 0; u < 4; ++u) {          // stage B (W rows)
            int ch = tid + 256*u;
            int r = ch >> 4, c = (ch & 15) * 4;
            float4 wv = *reinterpret_cast<const float4*>(W + (size_t)(n0 + r)*512 + k0 + c);
            short4v sv = { f2bf(wv.x), f2bf(wv.y), f2bf(wv.z), f2bf(wv.w) };
            *reinterpret_cast<short4v*>(&Bs[r][c]) = sv;
        }
        __syncthreads();
        #pragma unroll
        for (int ks = 0; ks < 2; ++ks) {
            short8v a = *reinterpret_cast<const short8v*>(&As[16*w + lm][ks*32 + 8*g]);
            #pragma unroll
            for (int nt = 0; nt < 4; ++nt) {
                short8v bv = *reinterpret_cast<const short8v*>(&Bs[16*nt + lm][ks*32 + 8*g]);
                acc[nt] = __builtin_amdgcn_mfma_f32_16x16x32_bf16(a, bv, acc[nt], 0, 0, 0);
            }
        }
    }
    #pragma unroll
    for (int nt = 0; nt < 4; ++nt)
        #pragma unroll
        for (int r = 0; r < 4; ++r) {
            int row = m0 + 16*w + 4*g + r;     // D: row = 4*(lane>>4)+reg, col = lane&15
            int col = n0 + 16*nt + lm;
            C[(size_t)row*512 + col] = __float2bfloat16(acc[nt][r] * alpha);
        }
}

// ============ V transpose with sigma-permuted columns ============
// vt[b][d][32-block of t, order pos(tau)]: pos(tau) = 8*((tau&15)>>2) + (tau&3) + 4*(tau>>4)
// -> position 8g+e within a 32-key block holds key sigma(g,e) = {4g+e, 16+4g+(e-4)}.
__global__ __launch_bounds__(256) void transpose_v(
    const __hip_bfloat16* __restrict__ vin, __hip_bfloat16* __restrict__ vout)
{
    const int tid = threadIdx.x;
    const int b = blockIdx.y;
    const int t = blockIdx.x * 32 + (tid & 31);
    const int tau = t & 31;
    const int tp = (t & ~31) + 8*((tau & 15) >> 2) + (tau & 3) + 4*(tau >> 4);
    const short* src = (const short*)vin + (size_t)(b*TT + t)*D;
    short* dst = (short*)vout + (size_t)b*D*TT;
    #pragma unroll
    for (int u = 0; u < 8; ++u) {
        int cf = (tid >> 5) + 8*u;             // 0..63 (16B chunk within row)
        short8v vv = *reinterpret_cast<const short8v*>(src + cf*8);
        #pragma unroll
        for (int i = 0; i < 8; ++i)
            dst[(size_t)(cf*8 + i)*TT + tp] = vv[i];
    }
}

// ============ Flash attention: 4 waves = 2 q-groups x 2 d-halves ============
// TLP round: K double-buffered in 64KB LDS (only LDS user) -> 2 blocks/CU co-resident,
// 8 waves/CU = 2/SIMD. V direct from sigma-permuted global vt into named register batches
// (batch A issued before QK, batch B before softmax -> L2 latency hides under compute).
// launch_bounds(256,1): VGPR free to ~200 so the V batches actually stay hoisted (R5/R7's
// sink failures were the VGPR-128 cap). R9's verified pieces kept: dbuf-K source-XOR
// swizzle, pointer-toggle addressing, defer-max (THR=8), per-lane partial l, 4-chain QK.
__global__ __launch_bounds__(256, 1) void attn(
    const __hip_bfloat16* __restrict__ qg, const __hip_bfloat16* __restrict__ kg,
    const __hip_bfloat16* __restrict__ vtg, __hip_bfloat16* __restrict__ ctx)
{
    __shared__ short Ks[2][KT][512];           // 64KB; row r chunk c holds K chunk c^((r&15)<<2)

    const int tid = threadIdx.x;
    const int w = tid >> 6, lane = tid & 63, lm = lane & 15, g = lane >> 4;
    const int qgp = w & 1, dh = w >> 1;
    const int idx = blockIdx.x;
    const int b  = idx & 3;                    // batch -> XCD spread
    const int qb = 127 - (idx >> 2);           // descending work order
    const int qbase = qb * 32;
    const int qrow  = qbase + 16*qgp + lm;

    const short* qp = (const short*)qg  + (size_t)b*TT*D;
    const short* kp = (const short*)kg  + (size_t)b*TT*D;
    const short* vp = (const short*)vtg + (size_t)b*D*TT;

    // hoist Q fragments: lane (g,lm) holds Q[qrow][32s+8g .. +8]
    short8v qf[16];
    #pragma unroll
    for (int s = 0; s < 16; ++s)
        qf[s] = *reinterpret_cast<const short8v*>(qp + (size_t)qrow*D + 32*s + 8*g);

    float4v acc[16];                           // O^T: col=q=lm, rows=dims 256*dh+16*dt+4g+r
    #pragma unroll
    for (int i = 0; i < 16; ++i) acc[i] = (float4v){0.f,0.f,0.f,0.f};
    float m_r = -INFINITY, l_par = 0.f;        // l_par: this lane's 8-kj partial sum

    const int ntiles = qb + 1;

    // per-lane LDS base pointers (element = short)
    const short* k0p = &Ks[0][lm][g*8];        // K read: a0 = kc + 32*(s^lm); a1 = +8192
    const short* k1p = &Ks[1][lm][g*8];
    // per-lane global V base: dt stride = 16*TT shorts, tile offset = ks0
    const short* vbase = vp + (size_t)(256*dh + lm)*TT + 8*g;

    // stage K tile T into buffer BUF; source pre-XOR-swizzled (rule #21)
    #define STAGE_K(T, BUF) do {                                                   \
        const short* kt_ = kp + (size_t)(T) * KT * D;                              \
        _Pragma("unroll")                                                          \
        for (int i_ = 0; i_ < 8; ++i_) {                                           \
            int r_ = 8*w + i_;                                                     \
            int c_ = (lane ^ ((r_ & 15) << 2)) & 63;                               \
            __builtin_amdgcn_global_load_lds(                                      \
                (const __attribute__((address_space(1))) void*)(kt_ + (size_t)r_*D + c_*8), \
                (__attribute__((address_space(3))) void*)(&Ks[BUF][r_][0]),        \
                16, 0, 0);                                                         \
        }                                                                          \
    } while (0)

    STAGE_K(0, 0);

    for (int t = 0; t < ntiles; ++t) {
        const int ks0 = t * KT;
        __syncthreads();                       // own vmcnt drained pre-barrier -> stage(t)
                                               // landed for all waves; reads of t-1 done
        if (t + 1 < ntiles) STAGE_K(t + 1, (t + 1) & 1);

        const short* kc = (t & 1) ? k1p : k0p;

        // V batch A (dims 256dh + 16*{0..7}): issue before QK, consumed in PV
        short8v vfa[8];
        #pragma unroll
        for (int dt = 0; dt < 8; ++dt)
            vfa[dt] = *reinterpret_cast<const short8v*>(vbase + (size_t)dt*16*TT + ks0);

        // S^T[kj][q]: 4 independent 8-deep MFMA chains
        float4v s0a = (float4v){0.f,0.f,0.f,0.f}, s0b = (float4v){0.f,0.f,0.f,0.f};
        float4v s1a = (float4v){0.f,0.f,0.f,0.f}, s1b = (float4v){0.f,0.f,0.f,0.f};
        #pragma unroll
        for (int s = 0; s < 16; ++s) {
            int off = (s ^ lm) << 5;           // shorts: 32*(s^lm)
            short8v a0 = *reinterpret_cast<const short8v*>(kc + off);
            short8v a1 = *reinterpret_cast<const short8v*>(kc + off + 8192);
            if (s & 1) {
                s0b = __builtin_amdgcn_mfma_f32_16x16x32_bf16(a0, qf[s], s0b, 0, 0, 0);
                s1b = __builtin_amdgcn_mfma_f32_16x16x32_bf16(a1, qf[s], s1b, 0, 0, 0);
            } else {
                s0a = __builtin_amdgcn_mfma_f32_16x16x32_bf16(a0, qf[s], s0a, 0, 0, 0);
                s1a = __builtin_amdgcn_mfma_f32_16x16x32_bf16(a1, qf[s], s1a, 0, 0, 0);
            }
        }

        // V batch B: issue before softmax so latency hides under it
        short8v vfb[8];
        #pragma unroll
        for (int dt = 0; dt < 8; ++dt)
            vfb[dt] = *reinterpret_cast<const short8v*>(vbase + (size_t)(8 + dt)*16*TT + ks0);

        float4v s0, s1;
        #pragma unroll
        for (int r = 0; r < 4; ++r) { s0[r] = s0a[r] + s0b[r]; s1[r] = s1a[r] + s1b[r]; }

        // causal mask; lane holds kj = ks0 + sigma(g,e) for q = qrow
        float p[8];
        #pragma unroll
        for (int r = 0; r < 4; ++r) {
            int kj0 = ks0 + 4*g + r;
            p[r]     = (kj0      <= qrow) ? s0[r] : -3.0e38f;
            p[r + 4] = (kj0 + 16 <= qrow) ? s1[r] : -3.0e38f;
        }
        float mx = p[0];
        #pragma unroll
        for (int i = 1; i < 8; ++i) mx = fmaxf(mx, p[i]);

        // defer-max: row-max shuffles + rescale only when slack exceeded (or first tile)
        if (!__all(mx <= m_r + 8.f)) {
            float mrow = fmaxf(mx, __shfl_xor(mx, 16));
            mrow = fmaxf(mrow, __shfl_xor(mrow, 32));
            mrow = fmaxf(mrow, m_r);
            float corr = __expf(m_r - mrow);   // first tile: expf(-inf)=0
            m_r = mrow;
            l_par *= corr;
            #pragma unroll
            for (int dt = 0; dt < 16; ++dt) {
                acc[dt][0] *= corr; acc[dt][1] *= corr;
                acc[dt][2] *= corr; acc[dt][3] *= corr;
            }
        }
        #pragma unroll
        for (int i = 0; i < 8; ++i) { p[i] = __expf(p[i] - m_r); l_par += p[i]; }

        // P fragment (lane-local): B-operand elems = P[q=lm][sigma(g,e)], values <= e^8
        short8v pf;
        #pragma unroll
        for (int i = 0; i < 8; ++i) pf[i] = f2bf(p[i]);

        // PV (O^T): A = V^T rows from registers, B = pf
        #pragma unroll
        for (int dt = 0; dt < 8; ++dt)
            acc[dt] = __builtin_amdgcn_mfma_f32_16x16x32_bf16(vfa[dt], pf, acc[dt], 0, 0, 0);
        #pragma unroll
        for (int dt = 0; dt < 8; ++dt)
            acc[8 + dt] = __builtin_amdgcn_mfma_f32_16x16x32_bf16(vfb[dt], pf, acc[8 + dt], 0, 0, 0);
    }
    #undef STAGE_K

    // epilogue: reduce l across the row's 4 g-lanes, then lane-local normalize
    float l = l_par + __shfl_xor(l_par, 16);
    l += __shfl_xor(l, 32);
    float inv = 1.f / l;
    __hip_bfloat16* cp = ctx + (size_t)b*TT*D;
    const int orow = qbase + 16*qgp + lm;
    #pragma unroll
    for (int dt = 0; dt < 16; ++dt) {
        short4v o = { f2bf(acc[dt][0]*inv), f2bf(acc[dt][1]*inv),
                      f2bf(acc[dt][2]*inv), f2bf(acc[dt][3]*inv) };
        *reinterpret_cast<short4v*>((short*)cp + (size_t)orow*D + 256*dh + 16*dt + 4*g) = o;
    }
}

// ============ Output projection: d_out[t][e] = sum_d ctx[t][d] * Wo[e][d], f32 out ============
__global__ __launch_bounds__(256) void gemm_out(
    const __hip_bfloat16* __restrict__ Ab, const float* __restrict__ W,
    float* __restrict__ Cf)
{
    __shared__ short As[64][72];
    __shared__ short Bs[64][72];
    const int tid = threadIdx.x;
    const int m0 = blockIdx.x * 64, n0 = blockIdx.y * 64;
    const int w = tid >> 6, lane = tid & 63, lm = lane & 15, g = lane >> 4;
    const short* Ap = (const short*)Ab;

    float4v acc[4];
    #pragma unroll
    for (int i = 0; i < 4; ++i) acc[i] = (float4v){0.f,0.f,0.f,0.f};

    for (int k0 = 0; k0 < 512; k0 += 64) {
        __syncthreads();
        #pragma unroll
        for (int u = 0; u < 2; ++u) {          // stage A (bf16 ctx)
            int ch = tid + 256*u;
            int r = ch >> 3, c = (ch & 7) * 8;
            *reinterpret_cast<short8v*>(&As[r][c]) =
                *reinterpret_cast<const short8v*>(Ap + (size_t)(m0 + r)*512 + k0 + c);
        }
        #pragma unroll
        for (int u = 0; u < 4; ++u) {          // stage B (Wo f32 -> bf16)
            int ch = tid + 256*u;
            int r = ch >> 4, c = (ch & 15) * 4;
            float4 wv = *reinterpret_cast<const float4*>(W + (size_t)(n0 + r)*512 + k0 + c);
            short4v sv = { f2bf(wv.x), f2bf(wv.y), f2bf(wv.z), f2bf(wv.w) };
            *reinterpret_cast<short4v*>(&Bs[r][c]) = sv;
        }
        __syncthreads();
        #pragma unroll
        for (int ks = 0; ks < 2; ++ks) {
            short8v a = *reinterpret_cast<const short8v*>(&As[16*w + lm][ks*32 + 8*g]);
            #pragma unroll
            for (int nt = 0; nt < 4; ++nt) {
                short8v bv = *reinterpret_cast<const short8v*>(&Bs[16*nt + lm][ks*32 + 8*g]);
                acc[nt] = __builtin_amdgcn_mfma_f32_16x16x32_bf16(a, bv, acc[nt], 0, 0, 0);
            }
        }
    }
    #pragma unroll
    for (int nt = 0; nt < 4; ++nt)
        #pragma unroll
        for (int r = 0; r < 4; ++r) {
            int row = m0 + 16*w + 4*g + r;
            int col = n0 + 16*nt + lm;
            Cf[(size_t)row*512 + col] = acc[nt][r];
        }
}

extern "C" void kernel_launch(void* const* d_in, const int* in_sizes, int n_in,
                              void* d_out, int out_size, void* d_ws, size_t ws_size,
                              hipStream_t stream) {
    const float* x  = (const float*)d_in[0];
    const float* Wq = (const float*)d_in[1];
    const float* Wk = (const float*)d_in[2];
    const float* Wv = (const float*)d_in[3];
    const float* Wo = (const float*)d_in[4];
    float* out = (float*)d_out;

    const size_t n = (size_t)BB * TT * D;                 // 8.4M elems
    __hip_bfloat16* qb   = (__hip_bfloat16*)d_ws;
    __hip_bfloat16* kb   = qb + n;
    __hip_bfloat16* vb   = kb + n;
    __hip_bfloat16* vt   = vb + n;
    __hip_bfloat16* ctxb = vt + n;                        // total 5n*2B = 80MB

    gemm_qkv<<<dim3(256, 8, 3), 256, 0, stream>>>(x, Wq, Wk, Wv, qb, kb, vb);
    transpose_v<<<dim3(TT / 32, BB), 256, 0, stream>>>(vb, vt);
    attn<<<dim3(128 * BB), 256, 0, stream>>>(qb, kb, vt, ctxb);
    gemm_out<<<dim3(256, 8, 1), 256, 0, stream>>>(ctxb, Wo, out);
}

// Round 11
// 382.533 us; speedup vs baseline: 1.2421x; 1.2421x over previous
//
#include <hip/hip_runtime.h>
#include <hip/hip_bf16.h>
#include <math.h>

#define D 512
#define BB 4
#define TT 4096
#define KT 32

typedef __attribute__((ext_vector_type(8))) short short8v;
typedef __attribute__((ext_vector_type(4))) short short4v;
typedef __attribute__((ext_vector_type(4))) float float4v;

__device__ inline short f2bf(float x) {
    __hip_bfloat16 h = __float2bfloat16(x);
    return *reinterpret_cast<short*>(&h);
}

// ============ QKV projection: C[t][e] = alpha * sum_d x[t][d] * W[e][d], bf16 out ============
__global__ __launch_bounds__(256) void gemm_qkv(
    const float* __restrict__ x,
    const float* __restrict__ Wq, const float* __restrict__ Wk, const float* __restrict__ Wv,
    __hip_bfloat16* __restrict__ q, __hip_bfloat16* __restrict__ k, __hip_bfloat16* __restrict__ v)
{
    const float* W; __hip_bfloat16* C; float alpha;
    if (blockIdx.z == 0)      { W = Wq; C = q; alpha = 0.044194173824159216f; } // fold 1/sqrt(512)
    else if (blockIdx.z == 1) { W = Wk; C = k; alpha = 1.f; }
    else                      { W = Wv; C = v; alpha = 1.f; }

    __shared__ short As[64][72];   // +8 bf16 pad -> conflict-floor b128 reads
    __shared__ short Bs[64][72];
    const int tid = threadIdx.x;
    const int m0 = blockIdx.x * 64, n0 = blockIdx.y * 64;
    const int w = tid >> 6, lane = tid & 63, lm = lane & 15, g = lane >> 4;

    float4v acc[4];
    #pragma unroll
    for (int i = 0; i < 4; ++i) acc[i] = (float4v){0.f,0.f,0.f,0.f};

    for (int k0 = 0; k0 < 512; k0 += 64) {
        __syncthreads();
        #pragma unroll
        for (int u = 0; u < 4; ++u) {          // stage A (x), convert f32->bf16
            int ch = tid + 256*u;
            int r = ch >> 4, c = (ch & 15) * 4;
            float4 xv = *reinterpret_cast<const float4*>(x + (size_t)(m0 + r)*512 + k0 + c);
            short4v sv = { f2bf(xv.x), f2bf(xv.y), f2bf(xv.z), f2bf(xv.w) };
            *reinterpret_cast<short4v*>(&As[r][c]) = sv;
        }
        #pragma unroll
        for (int u = 0; u < 4; ++u) {          // stage B (W rows)
            int ch = tid + 256*u;
            int r = ch >> 4, c = (ch & 15) * 4;
            float4 wv = *reinterpret_cast<const float4*>(W + (size_t)(n0 + r)*512 + k0 + c);
            short4v sv = { f2bf(wv.x), f2bf(wv.y), f2bf(wv.z), f2bf(wv.w) };
            *reinterpret_cast<short4v*>(&Bs[r][c]) = sv;
        }
        __syncthreads();
        #pragma unroll
        for (int ks = 0; ks < 2; ++ks) {
            short8v a = *reinterpret_cast<const short8v*>(&As[16*w + lm][ks*32 + 8*g]);
            #pragma unroll
            for (int nt = 0; nt < 4; ++nt) {
                short8v bv = *reinterpret_cast<const short8v*>(&Bs[16*nt + lm][ks*32 + 8*g]);
                acc[nt] = __builtin_amdgcn_mfma_f32_16x16x32_bf16(a, bv, acc[nt], 0, 0, 0);
            }
        }
    }
    #pragma unroll
    for (int nt = 0; nt < 4; ++nt)
        #pragma unroll
        for (int r = 0; r < 4; ++r) {
            int row = m0 + 16*w + 4*g + r;     // D: row = 4*(lane>>4)+reg, col = lane&15
            int col = n0 + 16*nt + lm;
            C[(size_t)row*512 + col] = __float2bfloat16(acc[nt][r] * alpha);
        }
}

// ============ V transpose with sigma-permuted columns ============
// vt[b][d][32-block of t, order pos(tau)]: pos(tau) = 8*((tau&15)>>2) + (tau&3) + 4*(tau>>4)
// -> position 8g+e within a 32-key block holds key sigma(g,e) = {4g+e, 16+4g+(e-4)}.
__global__ __launch_bounds__(256) void transpose_v(
    const __hip_bfloat16* __restrict__ vin, __hip_bfloat16* __restrict__ vout)
{
    const int tid = threadIdx.x;
    const int b = blockIdx.y;
    const int t = blockIdx.x * 32 + (tid & 31);
    const int tau = t & 31;
    const int tp = (t & ~31) + 8*((tau & 15) >> 2) + (tau & 3) + 4*(tau >> 4);
    const short* src = (const short*)vin + (size_t)(b*TT + t)*D;
    short* dst = (short*)vout + (size_t)b*D*TT;
    #pragma unroll
    for (int u = 0; u < 8; ++u) {
        int cf = (tid >> 5) + 8*u;             // 0..63 (16B chunk within row)
        short8v vv = *reinterpret_cast<const short8v*>(src + cf*8);
        #pragma unroll
        for (int i = 0; i < 8; ++i)
            dst[(size_t)(cf*8 + i)*TT + tp] = vv[i];
    }
}

// ============ Flash attention: triangle-paired two-phase blocks ============
// R9's verified kernel (K+V double-buffered LDS, source-XOR swizzles, pointer-toggle
// addressing, O^T PV, defer-max, per-lane l) wrapped in a 2-phase loop: block pr handles
// q-tile pr (tiles 0..pr) then q-tile 127-pr (tiles 0..127-pr) -> EVERY block runs exactly
// 129 tiles. 256 blocks = 1/CU: perfect load balance, no sequential-second-block penalty.
__global__ __launch_bounds__(256, 1) void attn(
    const __hip_bfloat16* __restrict__ qg, const __hip_bfloat16* __restrict__ kg,
    const __hip_bfloat16* __restrict__ vtg, __hip_bfloat16* __restrict__ ctx)
{
    __shared__ short Ks[2][KT][512];           // 64KB; row r chunk c holds K chunk c^((r&15)<<2)
    __shared__ short Vs[2][512][32];           // 64KB; row d chunk c holds vt chunk c^((d>>1)&3)

    const int tid = threadIdx.x;
    const int w = tid >> 6, lane = tid & 63, lm = lane & 15, g = lane >> 4;
    const int qgp = w & 1, dh = w >> 1;
    const int idx = blockIdx.x;
    const int b  = idx & 3;                    // batch -> XCD spread
    const int pr = idx >> 2;                   // pair index 0..63

    const short* qp = (const short*)qg  + (size_t)b*TT*D;
    const short* kp = (const short*)kg  + (size_t)b*TT*D;
    const short* vp = (const short*)vtg + (size_t)b*D*TT;
    __hip_bfloat16* cp = ctx + (size_t)b*TT*D;

    const int vswz = (lane & 3) ^ ((lane >> 3) & 3);   // V stage: source chunk for this lane

    // per-lane LDS base pointers (element = short)
    const short* k0p = &Ks[0][lm][g*8];        // K read: a0 = kc + 32*(s^lm); a1 = +8192
    const short* k1p = &Ks[1][lm][g*8];
    const int vcid = g ^ ((lm >> 1) & 3);
    const short* v0p = &Vs[0][256*dh + lm][vcid*8];    // PV read: vc + dt*512 (literal)
    const short* v1p = &Vs[1][256*dh + lm][vcid*8];

    // stage tile T (K rows + V^T dims) into buffer BUF; source pre-XOR-swizzled (rule #21)
    #define STAGE_KV(T, BUF) do {                                                  \
        const short* kt_ = kp + (size_t)(T) * KT * D;                              \
        const int ksv_ = (T) * KT;                                                 \
        _Pragma("unroll")                                                          \
        for (int i_ = 0; i_ < 8; ++i_) {                                           \
            int r_ = 8*w + i_;                                                     \
            int c_ = (lane ^ ((r_ & 15) << 2)) & 63;                               \
            __builtin_amdgcn_global_load_lds(                                      \
                (const __attribute__((address_space(1))) void*)(kt_ + (size_t)r_*D + c_*8), \
                (__attribute__((address_space(3))) void*)(&Ks[BUF][r_][0]),        \
                16, 0, 0);                                                         \
        }                                                                          \
        _Pragma("unroll")                                                          \
        for (int i_ = 0; i_ < 8; ++i_) {                                           \
            int d0_ = 128*w + 16*i_;                                               \
            int row_ = d0_ + (lane >> 2);                                          \
            __builtin_amdgcn_global_load_lds(                                      \
                (const __attribute__((address_space(1))) void*)(vp + (size_t)row_*TT + ksv_ + vswz*8), \
                (__attribute__((address_space(3))) void*)(&Vs[BUF][d0_][0]),       \
                16, 0, 0);                                                         \
        }                                                                          \
    } while (0)

    #pragma unroll 1
    for (int phase = 0; phase < 2; ++phase) {
        const int qb = phase ? (127 - pr) : pr;
        const int qbase = qb * 32;
        const int qrow  = qbase + 16*qgp + lm;
        const int ntiles = qb + 1;

        // hoist Q fragments for this phase: lane (g,lm) holds Q[qrow][32s+8g .. +8]
        short8v qf[16];
        #pragma unroll
        for (int s = 0; s < 16; ++s)
            qf[s] = *reinterpret_cast<const short8v*>(qp + (size_t)qrow*D + 32*s + 8*g);

        float4v acc[16];                       // O^T: col=q=lm, rows=dims 256*dh+16*dt+4g+r
        #pragma unroll
        for (int i = 0; i < 16; ++i) acc[i] = (float4v){0.f,0.f,0.f,0.f};
        float m_r = -INFINITY, l_par = 0.f;    // l_par: this lane's 8-kj partial sum

        __syncthreads();                       // prev phase's LDS reads done before re-staging
        STAGE_KV(0, 0);

        for (int t = 0; t < ntiles; ++t) {
            const int ks0 = t * KT;
            __syncthreads();                   // own vmcnt drained pre-barrier -> stage(t)
                                               // landed for all waves; reads of t-1 done
            if (t + 1 < ntiles) STAGE_KV(t + 1, (t + 1) & 1);

            const short* kc = (t & 1) ? k1p : k0p;
            const short* vc = (t & 1) ? v1p : v0p;

            // S^T[kj][q]: 4 independent 8-deep MFMA chains
            float4v s0a = (float4v){0.f,0.f,0.f,0.f}, s0b = (float4v){0.f,0.f,0.f,0.f};
            float4v s1a = (float4v){0.f,0.f,0.f,0.f}, s1b = (float4v){0.f,0.f,0.f,0.f};
            #pragma unroll
            for (int s = 0; s < 16; ++s) {
                int off = (s ^ lm) << 5;       // shorts: 32*(s^lm)
                short8v a0 = *reinterpret_cast<const short8v*>(kc + off);
                short8v a1 = *reinterpret_cast<const short8v*>(kc + off + 8192);
                if (s & 1) {
                    s0b = __builtin_amdgcn_mfma_f32_16x16x32_bf16(a0, qf[s], s0b, 0, 0, 0);
                    s1b = __builtin_amdgcn_mfma_f32_16x16x32_bf16(a1, qf[s], s1b, 0, 0, 0);
                } else {
                    s0a = __builtin_amdgcn_mfma_f32_16x16x32_bf16(a0, qf[s], s0a, 0, 0, 0);
                    s1a = __builtin_amdgcn_mfma_f32_16x16x32_bf16(a1, qf[s], s1a, 0, 0, 0);
                }
            }
            float4v s0, s1;
            #pragma unroll
            for (int r = 0; r < 4; ++r) { s0[r] = s0a[r] + s0b[r]; s1[r] = s1a[r] + s1b[r]; }

            // causal mask; lane holds kj = ks0 + sigma(g,e) for q = qrow
            float p[8];
            #pragma unroll
            for (int r = 0; r < 4; ++r) {
                int kj0 = ks0 + 4*g + r;
                p[r]     = (kj0      <= qrow) ? s0[r] : -3.0e38f;
                p[r + 4] = (kj0 + 16 <= qrow) ? s1[r] : -3.0e38f;
            }
            float mx = p[0];
            #pragma unroll
            for (int i = 1; i < 8; ++i) mx = fmaxf(mx, p[i]);

            // defer-max: row-max shuffles + rescale only when slack exceeded (or first tile)
            if (!__all(mx <= m_r + 8.f)) {
                float mrow = fmaxf(mx, __shfl_xor(mx, 16));
                mrow = fmaxf(mrow, __shfl_xor(mrow, 32));
                mrow = fmaxf(mrow, m_r);
                float corr = __expf(m_r - mrow);   // first tile: expf(-inf)=0
                m_r = mrow;
                l_par *= corr;
                #pragma unroll
                for (int dt = 0; dt < 16; ++dt) {
                    acc[dt][0] *= corr; acc[dt][1] *= corr;
                    acc[dt][2] *= corr; acc[dt][3] *= corr;
                }
            }
            #pragma unroll
            for (int i = 0; i < 8; ++i) { p[i] = __expf(p[i] - m_r); l_par += p[i]; }

            // P fragment (lane-local): B-operand elems = P[q=lm][sigma(g,e)], values <= e^8
            short8v pf;
            #pragma unroll
            for (int i = 0; i < 8; ++i) pf[i] = f2bf(p[i]);

            // PV (O^T): A = V^T rows from LDS at literal offsets, B = pf
            #pragma unroll
            for (int dt = 0; dt < 16; ++dt) {
                short8v vf = *reinterpret_cast<const short8v*>(vc + dt*512);
                acc[dt] = __builtin_amdgcn_mfma_f32_16x16x32_bf16(vf, pf, acc[dt], 0, 0, 0);
            }
        }

        // phase epilogue: reduce l across the row's 4 g-lanes, lane-local normalize, store
        float l = l_par + __shfl_xor(l_par, 16);
        l += __shfl_xor(l, 32);
        float inv = 1.f / l;
        const int orow = qbase + 16*qgp + lm;
        #pragma unroll
        for (int dt = 0; dt < 16; ++dt) {
            short4v o = { f2bf(acc[dt][0]*inv), f2bf(acc[dt][1]*inv),
                          f2bf(acc[dt][2]*inv), f2bf(acc[dt][3]*inv) };
            *reinterpret_cast<short4v*>((short*)cp + (size_t)orow*D + 256*dh + 16*dt + 4*g) = o;
        }
    }
    #undef STAGE_KV
}

// ============ Output projection: d_out[t][e] = sum_d ctx[t][d] * Wo[e][d], f32 out ============
__global__ __launch_bounds__(256) void gemm_out(
    const __hip_bfloat16* __restrict__ Ab, const float* __restrict__ W,
    float* __restrict__ Cf)
{
    __shared__ short As[64][72];
    __shared__ short Bs[64][72];
    const int tid = threadIdx.x;
    const int m0 = blockIdx.x * 64, n0 = blockIdx.y * 64;
    const int w = tid >> 6, lane = tid & 63, lm = lane & 15, g = lane >> 4;
    const short* Ap = (const short*)Ab;

    float4v acc[4];
    #pragma unroll
    for (int i = 0; i < 4; ++i) acc[i] = (float4v){0.f,0.f,0.f,0.f};

    for (int k0 = 0; k0 < 512; k0 += 64) {
        __syncthreads();
        #pragma unroll
        for (int u = 0; u < 2; ++u) {          // stage A (bf16 ctx)
            int ch = tid + 256*u;
            int r = ch >> 3, c = (ch & 7) * 8;
            *reinterpret_cast<short8v*>(&As[r][c]) =
                *reinterpret_cast<const short8v*>(Ap + (size_t)(m0 + r)*512 + k0 + c);
        }
        #pragma unroll
        for (int u = 0; u < 4; ++u) {          // stage B (Wo f32 -> bf16)
            int ch = tid + 256*u;
            int r = ch >> 4, c = (ch & 15) * 4;
            float4 wv = *reinterpret_cast<const float4*>(W + (size_t)(n0 + r)*512 + k0 + c);
            short4v sv = { f2bf(wv.x), f2bf(wv.y), f2bf(wv.z), f2bf(wv.w) };
            *reinterpret_cast<short4v*>(&Bs[r][c]) = sv;
        }
        __syncthreads();
        #pragma unroll
        for (int ks = 0; ks < 2; ++ks) {
            short8v a = *reinterpret_cast<const short8v*>(&As[16*w + lm][ks*32 + 8*g]);
            #pragma unroll
            for (int nt = 0; nt < 4; ++nt) {
                short8v bv = *reinterpret_cast<const short8v*>(&Bs[16*nt + lm][ks*32 + 8*g]);
                acc[nt] = __builtin_amdgcn_mfma_f32_16x16x32_bf16(a, bv, acc[nt], 0, 0, 0);
            }
        }
    }
    #pragma unroll
    for (int nt = 0; nt < 4; ++nt)
        #pragma unroll
        for (int r = 0; r < 4; ++r) {
            int row = m0 + 16*w + 4*g + r;
            int col = n0 + 16*nt + lm;
            Cf[(size_t)row*512 + col] = acc[nt][r];
        }
}

extern "C" void kernel_launch(void* const* d_in, const int* in_sizes, int n_in,
                              void* d_out, int out_size, void* d_ws, size_t ws_size,
                              hipStream_t stream) {
    const float* x  = (const float*)d_in[0];
    const float* Wq = (const float*)d_in[1];
    const float* Wk = (const float*)d_in[2];
    const float* Wv = (const float*)d_in[3];
    const float* Wo = (const float*)d_in[4];
    float* out = (float*)d_out;

    const size_t n = (size_t)BB * TT * D;                 // 8.4M elems
    __hip_bfloat16* qb   = (__hip_bfloat16*)d_ws;
    __hip_bfloat16* kb   = qb + n;
    __hip_bfloat16* vb   = kb + n;
    __hip_bfloat16* vt   = vb + n;
    __hip_bfloat16* ctxb = vt + n;                        // total 5n*2B = 80MB

    gemm_qkv<<<dim3(256, 8, 3), 256, 0, stream>>>(x, Wq, Wk, Wv, qb, kb, vb);
    transpose_v<<<dim3(TT / 32, BB), 256, 0, stream>>>(vb, vt);
    attn<<<dim3(64 * BB), 256, 0, stream>>>(qb, kb, vt, ctxb);
    gemm_out<<<dim3(256, 8, 1), 256, 0, stream>>>(ctxb, Wo, out);
}